// Round 1
// 405.563 us; speedup vs baseline: 1.0829x; 1.0829x over previous
//
#include <hip/hip_runtime.h>

// FinePreprocess: gather 5x5 windows (stride 4, pad 2) from two NCHW fp32
// feature maps at M random (batch, grid-idx) points.
// Output flat layout (per map): (M, C, 5, 5).
//
// R3: locality attack. R2 was DRAM-random-line bound:
//   FETCH 520 MB vs 153.6 MB exact (64-B line granularity on scattered 20-B
//   segments), combined 3.35 TB/s ~= the random-line HBM efficiency wall.
// Fix: device-side counting sort of the 12000 (map,point) jobs by
//   (map, b, gy) -> 480 buckets. One bucket's working set is
//   5 rows x 1280 B x 128 c ~= 820 KB -> fits a single XCD's 4 MB L2, and
//   adjacent-gx windows share 64-B lines. XCD-chunk swizzle keeps each
//   bucket's blocks on one XCD (no 8-way L2 replication of shared lines).
// Also: fast-path load is now 2 aligned float4 (col0-2 is 16-B aligned)
//   instead of f2+f2+scalar.

#define MPTS 6000
#define NPTS (2 * MPTS)
#define NCH  128
#define FH   240
#define FW   320
#define OUTW 80                 // (320 + 2*2 - 5)/4 + 1
#define OUTH 60
#define NKEY (2 * 4 * OUTH)     // 480 buckets: (map, b, gy)
#define PTFLOATS (NCH * 25)     // 3200 floats = 12.8 KB per (map, point)

// workspace layout (in ints)
#define WS_HIST   0             // [480]  histogram
#define WS_CURSOR 512           // [480]  scatter cursors
#define WS_BASE   1024          // [481]  exclusive-scan bases
#define WS_ORDER  2048          // [12000] sorted job ids (map*MPTS + m)
#define WS_INTS   (WS_ORDER + NPTS)

typedef float f2 __attribute__((ext_vector_type(2)));

__device__ __forceinline__ int point_key(int map, int b, int gy) {
    return (map * 4 + b) * OUTH + gy;
}

// ---- tiny sort pipeline ---------------------------------------------------

__global__ void k_zero(int* __restrict__ ws) {
    const int t = threadIdx.x;          // launched with 1024 threads
    if (t < WS_BASE) ws[t] = 0;         // zeroes hist + cursor regions
}

__global__ void k_hist(const int* __restrict__ b_ids,
                       const int* __restrict__ i_ids,
                       const int* __restrict__ j_ids,
                       int* __restrict__ ws) {
    const int t = blockIdx.x * blockDim.x + threadIdx.x;
    if (t >= NPTS) return;
    const int map = t >= MPTS;
    const int m   = map ? t - MPTS : t;
    const int idx = map ? j_ids[m] : i_ids[m];
    const int gy  = idx / OUTW;
    atomicAdd(&ws[WS_HIST + point_key(map, b_ids[m], gy)], 1);
}

__global__ void k_scan(int* __restrict__ ws) {
    __shared__ int h[NKEY];
    const int t = threadIdx.x;
    for (int i = t; i < NKEY; i += blockDim.x) h[i] = ws[WS_HIST + i];
    __syncthreads();
    if (t == 0) {
        int acc = 0;
        for (int i = 0; i < NKEY; i++) { int v = h[i]; h[i] = acc; acc += v; }
    }
    __syncthreads();
    for (int i = t; i < NKEY; i += blockDim.x) ws[WS_BASE + i] = h[i];
    if (t == 0) ws[WS_BASE + NKEY] = NPTS;
}

__global__ void k_scatter(const int* __restrict__ b_ids,
                          const int* __restrict__ i_ids,
                          const int* __restrict__ j_ids,
                          int* __restrict__ ws) {
    const int t = blockIdx.x * blockDim.x + threadIdx.x;
    if (t >= NPTS) return;
    const int map = t >= MPTS;
    const int m   = map ? t - MPTS : t;
    const int idx = map ? j_ids[m] : i_ids[m];
    const int gy  = idx / OUTW;
    const int key = point_key(map, b_ids[m], gy);
    const int pos = atomicAdd(&ws[WS_CURSOR + key], 1);
    ws[WS_ORDER + ws[WS_BASE + key] + pos] = t;
}

// ---- main gather ----------------------------------------------------------

__global__ __launch_bounds__(320) void fine_gather_kernel(
    const float* __restrict__ f0, const float* __restrict__ f1,
    const int* __restrict__ b_ids, const int* __restrict__ i_ids,
    const int* __restrict__ j_ids, const int* __restrict__ order,
    float* __restrict__ out)
{
    __shared__ __align__(16) float lds[PTFLOATS];

    // XCD-chunk swizzle: with bid%8 round-robin dispatch, XCD x gets the
    // contiguous sorted range [x*1500, (x+1)*1500) -> bucket lines stay in
    // one XCD's L2. Falls back to identity when no workspace.
    int ent;
    if (order) {
        const int pos = (blockIdx.x & 7) * (NPTS / 8) + (blockIdx.x >> 3);
        ent = order[pos];
    } else {
        ent = blockIdx.x;
    }

    const int map = ent >= MPTS;
    const int m   = map ? ent - MPTS : ent;
    const float* __restrict__ feat = map ? f1 : f0;
    const int idx = map ? j_ids[m] : i_ids[m];
    const int b   = b_ids[m];

    const int gy = idx / OUTW;
    const int gx = idx - gy * OUTW;
    const int row0 = gy * 4 - 2;           // top row of window (may be -2,-1)
    const int col0 = gx * 4 - 2;           // left col (even; OOB only if gx==0)

    const int t = threadIdx.x;

    // Phase 1: gather 640 segments (c=0..127, r=0..4), 2 per thread.
    // Max col touched: 79*4-2+4 = 318 < 320 -> only the LEFT edge can be OOB.
#pragma unroll
    for (int it = 0; it < 2; it++) {
        const int s = t + it * 320;
        const int c = s / 5;
        const int r = s - c * 5;
        const int row = row0 + r;
        const bool vrow = (row >= 0) & (row < FH);
        const float* src = feat + (((long)(b * NCH + c) * FH + row) * FW + col0);

        float v[5];
        if (vrow && (col0 >= 0)) {
            // col0 >= 0 implies gx >= 1 implies col0 >= 2, so (col0-2)*4 is a
            // 16-B-aligned in-bounds offset: two float4 loads cover cols
            // col0-2 .. col0+5.
            const float4* p = (const float4*)(src - 2);
            const float4 q0 = p[0];
            const float4 q1 = p[1];
            v[0] = q0.z; v[1] = q0.w; v[2] = q1.x; v[3] = q1.y; v[4] = q1.z;
        } else {
#pragma unroll
            for (int k = 0; k < 5; k++) {
                const int cc = col0 + k;
                v[k] = (vrow && cc >= 0) ? src[k] : 0.0f;
            }
        }
        const int base = s * 5;            // (c*5 + r) * 5 ; stride 5 -> no bank conflict
#pragma unroll
        for (int k = 0; k < 5; k++) lds[base + k] = v[k];
    }

    __syncthreads();

    // Phase 2: coalesced float4 store of the 12.8 KB tile.
    float4* __restrict__ dst = (float4*)(out + (long)ent * PTFLOATS);
    const float4* sl = (const float4*)lds;
    for (int i = t; i < PTFLOATS / 4; i += 320)   // 800 float4s
        dst[i] = sl[i];
}

// ---- launch ---------------------------------------------------------------

extern "C" void kernel_launch(void* const* d_in, const int* in_sizes, int n_in,
                              void* d_out, int out_size, void* d_ws, size_t ws_size,
                              hipStream_t stream) {
    const float* f0   = (const float*)d_in[0];
    const float* f1   = (const float*)d_in[1];
    // d_in[2] = hw0_f, d_in[3] = hw0_c — compile-time constants, unused
    const int* b_ids  = (const int*)d_in[4];
    const int* i_ids  = (const int*)d_in[5];
    const int* j_ids  = (const int*)d_in[6];
    float* out        = (float*)d_out;

    int* ws = (int*)d_ws;
    const bool have_ws = (ws != nullptr) && (ws_size >= (size_t)WS_INTS * sizeof(int));

    const int* order = nullptr;
    if (have_ws) {
        k_zero<<<1, 1024, 0, stream>>>(ws);
        k_hist<<<(NPTS + 255) / 256, 256, 0, stream>>>(b_ids, i_ids, j_ids, ws);
        k_scan<<<1, 512, 0, stream>>>(ws);
        k_scatter<<<(NPTS + 255) / 256, 256, 0, stream>>>(b_ids, i_ids, j_ids, ws);
        order = ws + WS_ORDER;
    }

    fine_gather_kernel<<<NPTS, 320, 0, stream>>>(f0, f1, b_ids, i_ids, j_ids, order, out);
}